// Round 7
// baseline (244.792 us; speedup 1.0000x reference)
//
#include <hip/hip_runtime.h>
#include <stdint.h>
#include <stddef.h>
#include <math.h>

#define E_ 32
#define H_ 128
#define V_ 32000
#define NB 32
#define NT 128
#define NCONS 224      // consumer blocks (bid 32..255)
#define NCHUNK 250     // 128-col vocab chunks; 224 owned + 26 rotating extras
#define NX (NCHUNK - NCONS)   // 26 extra chunks
#define WSTEPS 16      // pipeline window (steps per release)
#define NWIN (NT / WSTEPS)    // 8 windows

typedef float f32x4 __attribute__((ext_vector_type(4)));
typedef short s16x8 __attribute__((ext_vector_type(8)));

__device__ inline unsigned short f2bf(float f) {
  uint32_t u = __float_as_uint(f);
  return (unsigned short)((u + 0x7FFFu + ((u >> 16) & 1u)) >> 16);
}

__global__ void zero_cnt(int* cnt) {
  if (threadIdx.x < NWIN) cnt[threadIdx.x] = 0;
}

// Fused producer-consumer, grid 256 x 1024 (1 block/CU, co-resident).
//  bid 0..31: LSTM recurrence. thread=(j=tid>>3, g=(tid>>1)&3, q2=tid&1);
//    80 weight VGPRs/thread (no spill); activations via v_exp/v_rcp (no
//    libcalls); h written to LDS per step, flushed to hbf once per window
//    (per-step barrier waits LDS only, no global-store drain).
//  bid 32..255: vocab consumers (16 waves, 16 cols each); own chunk + rotating
//    duty chunk LDS-resident; h prefetch issued AFTER the barrier so its
//    latency drains under MFMA+stores instead of at the barrier.
__global__ __launch_bounds__(1024, 1)
void lstm_fused(const float* __restrict__ x,
                const float* __restrict__ Wf, const float* __restrict__ bWf,
                const float* __restrict__ Uf, const float* __restrict__ bUf,
                const float* __restrict__ Wi, const float* __restrict__ bWi,
                const float* __restrict__ Ui, const float* __restrict__ bUi,
                const float* __restrict__ Wc, const float* __restrict__ bWc,
                const float* __restrict__ Uc, const float* __restrict__ bUc,
                const float* __restrict__ Wo, const float* __restrict__ bWo,
                const float* __restrict__ Uo, const float* __restrict__ bUo,
                const float* __restrict__ Vw, const float* __restrict__ Vb,
                unsigned short* __restrict__ hbf,  // [NT][NB][H_] bf16 bits
                int* __restrict__ cnt,             // [NWIN] window counters
                float* __restrict__ out,           // [NB][NT][V_]
                float* __restrict__ hlast)         // [NB][H_]
{
  __shared__ __align__(16) unsigned char smem[81920];
  const int bid = blockIdx.x;
  const int tid = threadIdx.x;

  if (bid < NB) {
    // ---------------- producer: recurrence for batch `bid` ----------------
    float* xs  = reinterpret_cast<float*>(smem);           // [NT][E_] 16 KB
    float* hd  = reinterpret_cast<float*>(smem + 16384);   // [2][128]
    float* hfl = reinterpret_cast<float*>(smem + 17408);   // [16][128] window h

    const int j  = tid >> 3;         // 0..127
    const int g  = (tid >> 1) & 3;   // gate
    const int q2 = tid & 1;          // k-half

    const float* WL[4]  = {Wf, Wi, Wc, Wo};
    const float* UL[4]  = {Uf, Ui, Uc, Uo};
    const float* bWL[4] = {bWf, bWi, bWc, bWo};
    const float* bUL[4] = {bUf, bUi, bUc, bUo};

    f32x4 ur_[16];  // U[g][j][q2*64 .. +64)
    f32x4 wr_[4];   // W[g][j][q2*16 .. +16)
    {
      const f32x4* Up = reinterpret_cast<const f32x4*>(UL[g] + j * H_ + q2 * 64);
#pragma unroll
      for (int r = 0; r < 16; ++r) ur_[r] = Up[r];
      const f32x4* Wp = reinterpret_cast<const f32x4*>(WL[g] + j * E_ + q2 * 16);
#pragma unroll
      for (int r = 0; r < 4; ++r) wr_[r] = Wp[r];
    }
    const float bias = bWL[g][j] + bUL[g][j];

    for (int i = tid; i < NT * E_; i += 1024) xs[i] = x[bid * (NT * E_) + i];
    if (tid < 128) { hd[tid] = 0.f; hd[128 + tid] = 0.f; }
    float creg = 0.f;
    __syncthreads();

    for (int win = 0; win < NWIN; ++win) {
      for (int tt = 0; tt < WSTEPS; ++tt) {
        const int t = win * WSTEPS + tt;
        const int cur = t & 1, nxt = cur ^ 1;
        const f32x4* hq = reinterpret_cast<const f32x4*>(hd + cur * 128 + q2 * 64);
        const f32x4* xq = reinterpret_cast<const f32x4*>(xs + t * E_ + q2 * 16);

        f32x4 a0 = {0.f,0.f,0.f,0.f}, a1 = a0, a2 = a0, a3 = a0;
#pragma unroll
        for (int r = 0; r < 4; ++r) {
          if ((r & 3) == 0) a0 += wr_[r] * xq[r];
          else if ((r & 3) == 1) a1 += wr_[r] * xq[r];
          else if ((r & 3) == 2) a2 += wr_[r] * xq[r];
          else a3 += wr_[r] * xq[r];
        }
#pragma unroll
        for (int r = 0; r < 16; ++r) {
          if ((r & 3) == 0) a0 += ur_[r] * hq[r];
          else if ((r & 3) == 1) a1 += ur_[r] * hq[r];
          else if ((r & 3) == 2) a2 += ur_[r] * hq[r];
          else a3 += ur_[r] * hq[r];
        }
        f32x4 s4 = (a0 + a1) + (a2 + a3);
        float s = (s4.x + s4.y) + (s4.z + s4.w);
        s += __shfl_xor(s, 1);          // k-half reduce
        s += bias;

        // activation: sigmoid, or tanh = 2*sigmoid(2x)-1 for gate 2.
        // v_exp + v_rcp: abs err ~1e-6, amplified ~2e-4 in out (safe).
        float xin = (g == 2) ? s + s : s;
        float e = __expf(-xin);
        float rv = __builtin_amdgcn_rcpf(1.f + e);
        float val = (g == 2) ? 2.f * rv - 1.f : rv;

        float v1 = __shfl_xor(val, 2);  // gate g^1
        float v2 = __shfl_xor(val, 4);  // gate g^2
        float v3 = __shfl_xor(v1, 4);   // gate g^3
        float f_ = (g == 0) ? val : (g == 1) ? v1 : (g == 2) ? v2 : v3;
        float i_ = (g == 0) ? v1 : (g == 1) ? val : (g == 2) ? v3 : v2;
        float c_ = (g == 0) ? v2 : (g == 1) ? v3 : (g == 2) ? val : v1;
        float o_ = (g == 0) ? v3 : (g == 1) ? v2 : (g == 2) ? v1 : val;

        float cn = f_ * creg + i_ * c_;
        creg = cn;
        float tn = 2.f * __builtin_amdgcn_rcpf(1.f + __expf(-2.f * cn)) - 1.f;
        float hn = o_ * tn;

        if ((tid & 7) == 0) {           // writer lane (g==0, q2==0)
          hd[nxt * 128 + j] = hn;
          hfl[tt * 128 + j] = hn;
          if (t == NT - 1) hlast[bid * H_ + j] = hn;
        }
        __syncthreads();                // LDS-only drain: no global stores queued
      }
      // ---- window flush: hfl -> hbf (coalesced u32 stores), then release ----
      {
        const int t16 = tid >> 6;       // 0..15
        const int jp  = tid & 63;       // j-pair
        float f0 = hfl[t16 * 128 + jp * 2];
        float f1 = hfl[t16 * 128 + jp * 2 + 1];
        uint32_t pk = (uint32_t)f2bf(f0) | ((uint32_t)f2bf(f1) << 16);
        uint32_t* hb32 = reinterpret_cast<uint32_t*>(hbf);
        hb32[((size_t)(win * WSTEPS + t16) * NB + bid) * 64 + jp] = pk;
      }
      __syncthreads();                  // all waves' flush stores drained
      if (tid == 0)
        __hip_atomic_fetch_add(&cnt[win], 1, __ATOMIC_RELEASE,
                               __HIP_MEMORY_SCOPE_AGENT);
    }
    return;
  }

  // ---------------- consumer: own chunk + rotating duty chunk ----------------
  const int cid = bid - NB;                       // 0..223, owns chunk `cid`
  unsigned char* vwo = smem;                      // own  Vw [128][256 B] swizzled
  unsigned char* vwx = smem + 32768;              // duty Vw [128][256 B] swizzled
  unsigned char* hlb = smem + 65536;              // [2][32 rows][256 B] swizzled

  const int w = tid >> 6, lane = tid & 63;
  const int wr = w & 1, wc = w >> 1;              // m-tile 0..1, n-16-block 0..7
  const int l15 = lane & 15, lh = lane >> 4;

  // stage own Vw chunk: fp32 -> bf16 -> swizzled LDS (one-time)
  for (int u = tid; u < 2048; u += 1024) {        // unit = 8 k-elems of one row
    int n = u >> 4, kc = u & 15;
    const f32x4* src = reinterpret_cast<const f32x4*>(
        Vw + ((size_t)(cid * 128 + n)) * H_ + kc * 8);
    f32x4 a = src[0], b = src[1];
    s16x8 o;
    o[0] = (short)f2bf(a.x); o[1] = (short)f2bf(a.y);
    o[2] = (short)f2bf(a.z); o[3] = (short)f2bf(a.w);
    o[4] = (short)f2bf(b.x); o[5] = (short)f2bf(b.y);
    o[6] = (short)f2bf(b.z); o[7] = (short)f2bf(b.w);
    *reinterpret_cast<s16x8*>(vwo + n * 256 + ((kc * 16) ^ ((n & 7) << 4))) = o;
  }
  float vbo = Vb[cid * 128 + wc * 16 + l15];
  const int hb_ = tid >> 4, hkc_ = tid & 15;      // h-stage LDS slot (tid<512)
  const int hswz = hb_ * 256 + ((hkc_ * 16) ^ ((hb_ & 7) << 4));
  __syncthreads();

  for (int win = 0; win < NWIN; ++win) {
    if (tid == 0) {
      while (__hip_atomic_load(&cnt[win], __ATOMIC_RELAXED,
                               __HIP_MEMORY_SCOPE_AGENT) < NB)
        __builtin_amdgcn_s_sleep(16);
      (void)__hip_atomic_load(&cnt[win], __ATOMIC_ACQUIRE,
                              __HIP_MEMORY_SCOPE_AGENT);  // one L1/L2 invalidate
    }
    __syncthreads();

    // prefetch h for this window's step 0
    s16x8 hv = {};
    if (tid < 512)
      hv = *reinterpret_cast<const s16x8*>(
          hbf + (size_t)(win * WSTEPS) * (NB * H_) + tid * 8);

    // rotating duty: window `win` -> blocks 26*win .. 26*win+25 stage one extra
    const int k = cid - NX * win;
    const bool duty = (k >= 0) && (k < NX);
    int chunk_x = NCONS + k;
    float vbx = 0.f;
    if (duty) {
      for (int u = tid; u < 2048; u += 1024) {
        int n = u >> 4, kc = u & 15;
        const f32x4* src = reinterpret_cast<const f32x4*>(
            Vw + ((size_t)(chunk_x * 128 + n)) * H_ + kc * 8);
        f32x4 a = src[0], b = src[1];
        s16x8 o;
        o[0] = (short)f2bf(a.x); o[1] = (short)f2bf(a.y);
        o[2] = (short)f2bf(a.z); o[3] = (short)f2bf(a.w);
        o[4] = (short)f2bf(b.x); o[5] = (short)f2bf(b.y);
        o[6] = (short)f2bf(b.z); o[7] = (short)f2bf(b.w);
        *reinterpret_cast<s16x8*>(vwx + n * 256 + ((kc * 16) ^ ((n & 7) << 4))) = o;
      }
      vbx = Vb[chunk_x * 128 + wc * 16 + l15];
    }

    for (int tt = 0; tt < WSTEPS; ++tt) {
      const int t = win * WSTEPS + tt;
      unsigned char* hcur = hlb + (tt & 1) * 8192;
      if (tid < 512)
        *reinterpret_cast<s16x8*>(hcur + hswz) = hv;
      __syncthreads();
      // issue next step's h load AFTER the barrier: drains under MFMA+stores
      if (tt < WSTEPS - 1 && tid < 512)
        hv = *reinterpret_cast<const s16x8*>(
            hbf + (size_t)(t + 1) * (NB * H_) + tid * 8);

      s16x8 af[4];
      const int ra = wr * 16 + l15;
#pragma unroll
      for (int kt = 0; kt < 4; ++kt)
        af[kt] = *reinterpret_cast<const s16x8*>(
            hcur + ra * 256 + ((kt * 64 + lh * 16) ^ ((ra & 7) << 4)));

      const int rb = wc * 16 + l15;
      // own chunk
      {
        f32x4 acc = {0.f,0.f,0.f,0.f};
#pragma unroll
        for (int kt = 0; kt < 4; ++kt) {
          s16x8 b0 = *reinterpret_cast<const s16x8*>(
              vwo + rb * 256 + ((kt * 64 + lh * 16) ^ ((rb & 7) << 4)));
          acc = __builtin_amdgcn_mfma_f32_16x16x32_bf16(af[kt], b0, acc, 0, 0, 0);
        }
        const int colbase = cid * 128 + wc * 16;
#pragma unroll
        for (int i = 0; i < 4; ++i) {
          int b = wr * 16 + lh * 4 + i;
          out[((size_t)b * NT + t) * V_ + colbase + l15] = acc[i] + vbo;
        }
      }
      // duty chunk
      if (duty) {
        f32x4 acc = {0.f,0.f,0.f,0.f};
#pragma unroll
        for (int kt = 0; kt < 4; ++kt) {
          s16x8 b0 = *reinterpret_cast<const s16x8*>(
              vwx + rb * 256 + ((kt * 64 + lh * 16) ^ ((rb & 7) << 4)));
          acc = __builtin_amdgcn_mfma_f32_16x16x32_bf16(af[kt], b0, acc, 0, 0, 0);
        }
        const int colbase = chunk_x * 128 + wc * 16;
#pragma unroll
        for (int i = 0; i < 4; ++i) {
          int b = wr * 16 + lh * 4 + i;
          out[((size_t)b * NT + t) * V_ + colbase + l15] = acc[i] + vbx;
        }
      }
    }
  }
}

// ---------------------------------------------------------------------------
extern "C" void kernel_launch(void* const* d_in, const int* in_sizes, int n_in,
                              void* d_out, int out_size, void* d_ws, size_t ws_size,
                              hipStream_t stream) {
  const float* x   = (const float*)d_in[0];
  const float* Wf  = (const float*)d_in[1];
  const float* bWf = (const float*)d_in[2];
  const float* Uf  = (const float*)d_in[3];
  const float* bUf = (const float*)d_in[4];
  const float* Wi  = (const float*)d_in[5];
  const float* bWi = (const float*)d_in[6];
  const float* Ui  = (const float*)d_in[7];
  const float* bUi = (const float*)d_in[8];
  const float* Wc  = (const float*)d_in[9];
  const float* bWc = (const float*)d_in[10];
  const float* Uc  = (const float*)d_in[11];
  const float* bUc = (const float*)d_in[12];
  const float* Wo  = (const float*)d_in[13];
  const float* bWo = (const float*)d_in[14];
  const float* Uo  = (const float*)d_in[15];
  const float* bUo = (const float*)d_in[16];
  const float* Vw  = (const float*)d_in[17];
  const float* Vb  = (const float*)d_in[18];
  float* out = (float*)d_out;

  unsigned short* hbf = (unsigned short*)d_ws;                 // 1 MB [t][b][H]
  int* cnt = (int*)((char*)d_ws + (1u << 20));                 // 32 B
  float* hlast = out + (size_t)NB * NT * V_;

  hipLaunchKernelGGL(zero_cnt, dim3(1), dim3(64), 0, stream, cnt);
  hipLaunchKernelGGL(lstm_fused, dim3(256), dim3(1024), 0, stream,
                     x, Wf, bWf, Uf, bUf, Wi, bWi, Ui, bUi, Wc, bWc, Uc, bUc,
                     Wo, bWo, Uo, bUo, Vw, Vb, hbf, cnt, out, hlast);
}